// Round 9
// baseline (278.056 us; speedup 1.0000x reference)
//
#include <hip/hip_runtime.h>
#include <math.h>

#define NB   128
#define CF   1024
#define RR   256
#define NA   312
#define DV   300
#define MT   640
#define NKC  32
#define NQ   160
#define NPI  320          // padded i-pairs per (b,rh)
#define ACHUNK 40960      // Qb bytes per kc (640 rows x 64 B)
#define ATILE  12288      // LDS A tile: [4 kb][192 rows pad][16 B]

typedef _Float16 half8  __attribute__((ext_vector_type(8)));
typedef _Float16 half4  __attribute__((ext_vector_type(4)));
typedef float float16v  __attribute__((ext_vector_type(16)));
typedef float float4v   __attribute__((ext_vector_type(4)));

// async global->LDS, 16B/lane; dest = wave-uniform base + lane*16 (linear).
__device__ __forceinline__ void gll16(const void* g, void* l) {
    __builtin_amdgcn_global_load_lds(
        (const __attribute__((address_space(1))) void*)g,
        (__attribute__((address_space(3))) void*)l, 16, 0, 0);
}

// ---- K0: Q projection (pair-interleaved Qb rows: row 2i = Q1_i, 2i+1 = Q2_i) ----
__launch_bounds__(256, 4)
__global__ void k_q(const float* __restrict__ V, const float* __restrict__ W1,
                    const float* __restrict__ W2, _Float16* __restrict__ Qb) {
    int ib = blockIdx.x;
    int t  = threadIdx.x;
    bool isQ2 = ib >= 80;
    int i0l = (ib - (isQ2 ? 80 : 0)) * 4;
    __shared__ float inv4[4];
    float acc[4][4];
    #pragma unroll
    for (int ii = 0; ii < 4; ++ii)
        #pragma unroll
        for (int j = 0; j < 4; ++j) acc[ii][j] = 0.f;
    if (i0l < NA) {
        int row = t >> 6, l64 = t & 63;
        float s = 0.f;
        for (int v = l64; v < DV; v += 64) { float x = V[(i0l + row) * DV + v]; s += x * x; }
        #pragma unroll
        for (int o = 32; o; o >>= 1) s += __shfl_xor(s, o, 64);
        if (l64 == 0) inv4[row] = 1.f / fmaxf(sqrtf(s), 1e-12f);
        __syncthreads();
        const float* W  = isQ2 ? W2 : W1;
        const float* Vb = V + (size_t)i0l * DV;
        for (int v = 0; v < DV; v += 2) {
            float4v w0 = *(const float4v*)(W + (size_t)v * CF + t * 4);
            float4v w1 = *(const float4v*)(W + (size_t)(v + 1) * CF + t * 4);
            #pragma unroll
            for (int ii = 0; ii < 4; ++ii) {
                float a0 = Vb[(size_t)ii * DV + v];
                float a1 = Vb[(size_t)ii * DV + v + 1];
                #pragma unroll
                for (int j = 0; j < 4; ++j) acc[ii][j] += a0 * w0[j] + a1 * w1[j];
            }
        }
        #pragma unroll
        for (int ii = 0; ii < 4; ++ii)
            #pragma unroll
            for (int j = 0; j < 4; ++j) acc[ii][j] *= inv4[ii];
    }
    int fg = t >> 3;
    int fo = (t & 7) * 4;
    int q12 = isQ2 ? 1 : 0;
    #pragma unroll
    for (int ii = 0; ii < 4; ++ii) {
        half4 h;
        #pragma unroll
        for (int j = 0; j < 4; ++j) h[j] = (_Float16)acc[ii][j];
        *(half4*)&Qb[((size_t)fg * MT + (2 * (i0l + ii) + q12)) * 32 + fo] = h;
    }
}

// ---- K1: fused GEMM+norm+partial-softmax. block = (b, rh, mq):            ----
// ---- M=160 x N=128, 128 threads / 2 waves, 4 independent blocks per CU.   ----
__launch_bounds__(128, 2)
__global__ void k_fused(const float* __restrict__ img, const _Float16* __restrict__ Qb,
                        float* __restrict__ pm, float* __restrict__ ps,
                        float* __restrict__ pd) {
    __shared__ __align__(16) char smem_s[2 * ATILE];

    int lin = blockIdx.x;          // 0..1023
    int b   = lin & 127;           // all 8 subtiles of b share blockIdx%8 -> same XCD
    int sub = lin >> 7;            // 0..7
    int rh  = sub >> 2;            // r-half
    int mq  = sub & 3;             // M-quarter: Qb rows [mq*160, +160)

    int tid  = threadIdx.x;        // 0..127
    int lane = tid & 63;
    int wn   = tid >> 6;           // 0..1: cols [wn*64, +64) within this rh half
    int nl   = lane & 31;
    int kh   = lane >> 5;

    // A staging: slot s = kb*192 + r (row pad 160->192); 6 gll16/thread.
    int aG[6];
    #pragma unroll
    for (int j = 0; j < 6; ++j) {
        int s  = tid + j * 128;
        int kb = s / 192;
        int r  = s % 192;
        int rc = r < 160 ? r : 159;            // clamp pad rows (dup loads, unused)
        aG[j] = (mq * 160 + rc) * 64 + kb * 16;
    }
    const char* gA = (const char*)Qb;

    // B per-lane: cols c_lo = rh*128 + wn*64 + nl and c_lo+32; f = kc*32+kh*8+ks*16+j.
    int c_lo = wn * 64 + nl;
    const float* pB = img + (size_t)b * CF * RR + (size_t)rh * 128 + c_lo
                      + (size_t)kh * 8 * RR;

    float16v acc[5][2];
    #pragma unroll
    for (int i = 0; i < 5; ++i)
        #pragma unroll
        for (int j = 0; j < 2; ++j)
            #pragma unroll
            for (int gi = 0; gi < 16; ++gi) acc[i][j][gi] = 0.f;
    float ssq0 = 0.f, ssq1 = 0.f;
    float Bv0[2][8], Bv1[2][8];    // [ks][j]
    half8 bf0[2], bf1[2];

    #define AGLL(kc_, bsel) do {                                                   \
        int kcl = (kc_) < NKC ? (kc_) : (NKC - 1);                                 \
        const char* aS = gA + (size_t)kcl * ACHUNK;                                \
        char* buf_ = smem_s + (int)(bsel) * ATILE;                                 \
        _Pragma("unroll")                                                          \
        for (int j = 0; j < 6; ++j) gll16(aS + aG[j], buf_ + (tid + j * 128) * 16); \
    } while (0)

    #define BLOAD(kc_) do {                                                        \
        int kcl = (kc_) < NKC ? (kc_) : (NKC - 1);                                 \
        const float* p = pB + (size_t)kcl * 32 * RR;                               \
        _Pragma("unroll")                                                          \
        for (int ks = 0; ks < 2; ++ks)                                             \
            _Pragma("unroll")                                                      \
            for (int j = 0; j < 8; ++j) {                                          \
                Bv0[ks][j] = p[(size_t)(ks * 16 + j) * RR];                        \
                Bv1[ks][j] = p[(size_t)(ks * 16 + j) * RR + 32];                   \
            }                                                                      \
    } while (0)

    #define BCVT() do {                                                            \
        _Pragma("unroll")                                                          \
        for (int ks = 0; ks < 2; ++ks)                                             \
            _Pragma("unroll")                                                      \
            for (int j = 0; j < 8; ++j) {                                          \
                float x0 = Bv0[ks][j], x1 = Bv1[ks][j];                            \
                ssq0 += x0 * x0; ssq1 += x1 * x1;                                  \
                bf0[ks][j] = (_Float16)x0; bf1[ks][j] = (_Float16)x1;              \
            }                                                                      \
    } while (0)

    #define COMPUTE(bsel) do {                                                     \
        const char* Al = smem_s + (int)(bsel) * ATILE;                             \
        _Pragma("unroll")                                                          \
        for (int ks = 0; ks < 2; ++ks) {                                           \
            int kb = ks * 2 + kh;                                                  \
            _Pragma("unroll")                                                      \
            for (int mt = 0; mt < 5; ++mt) {                                       \
                half8 af = *(const half8*)(Al + (kb * 192 + mt * 32 + nl) * 16);   \
                acc[mt][0] = __builtin_amdgcn_mfma_f32_32x32x16_f16(af, bf0[ks], acc[mt][0], 0, 0, 0); \
                acc[mt][1] = __builtin_amdgcn_mfma_f32_32x32x16_f16(af, bf1[ks], acc[mt][1], 0, 0, 0); \
            }                                                                      \
        }                                                                          \
    } while (0)

    // prologue: establish queue invariant [B(kc)x32 older, A(kc+1)x6 younger]
    AGLL(0, 0);                                        // [A0:6]
    BLOAD(0);                                          // [A0:6, B0:32]
    asm volatile("s_waitcnt vmcnt(32)" ::: "memory");  // A0 landed
    __builtin_amdgcn_s_barrier();
    AGLL(1, 1);                                        // [B0:32, A1:6]
    __builtin_amdgcn_sched_barrier(0);

    #pragma unroll 1
    for (int kc = 0; kc < NKC; ++kc) {
        asm volatile("s_waitcnt vmcnt(6)" ::: "memory");   // B(kc) landed
        BCVT();
        BLOAD(kc + 1);                                     // [A(kc+1):6, B(kc+1):32]
        __builtin_amdgcn_sched_barrier(0);
        __builtin_amdgcn_s_setprio(1);
        COMPUTE(kc & 1);
        __builtin_amdgcn_s_setprio(0);
        __builtin_amdgcn_sched_barrier(0);
        asm volatile("s_waitcnt vmcnt(32)" ::: "memory");  // A(kc+1) landed (mine)
        __builtin_amdgcn_s_barrier();                      // pair-wave rendezvous
        AGLL(kc + 2, kc & 1);                              // [B(kc+1):32, A(kc+2):6]
        __builtin_amdgcn_sched_barrier(0);
    }
    asm volatile("s_waitcnt vmcnt(0) lgkmcnt(0)" ::: "memory");
    __builtin_amdgcn_s_barrier();
    __builtin_amdgcn_sched_barrier(0);
    #undef AGLL
    #undef BLOAD
    #undef BCVT
    #undef COMPUTE

    // ---- epilogue (aliases smem_s) ----
    float* mred = (float*)smem_s;                 // [2][80]
    float* mg   = (float*)(smem_s + 1024);        // [80]
    float* sred = (float*)(smem_s + 1536);        // [2][80]
    float* dred = (float*)(smem_s + 2560);        // [2][80]

    // column norms: lane-local kh-half sums; merge halves.
    ssq0 += __shfl_xor(ssq0, 32, 64);
    ssq1 += __shfl_xor(ssq1, 32, 64);
    float iv0 = 1.f / fmaxf(sqrtf(ssq0), 1e-12f);
    float iv1 = 1.f / fmaxf(sqrtf(ssq1), 1e-12f);
    #pragma unroll
    for (int mt = 0; mt < 5; ++mt)
        #pragma unroll
        for (int gi = 0; gi < 16; ++gi) {
            acc[mt][0][gi] *= iv0;
            acc[mt][1][gi] *= iv1;
        }

    // pass 1: per-pair max over this block's 128 r
    #pragma unroll
    for (int mt = 0; mt < 5; ++mt) {
        #pragma unroll
        for (int e = 0; e < 8; ++e) {
            int g = 2 * e;
            float mx = fmaxf(acc[mt][0][g], acc[mt][1][g]);
            #pragma unroll
            for (int off = 1; off <= 16; off <<= 1)
                mx = fmaxf(mx, __shfl_xor(mx, off, 64));
            if (nl == 0) {
                int row = (g & 3) + 8 * (g >> 2) + 4 * kh;     // even, 0..30
                mred[wn * 80 + mt * 16 + (row >> 1)] = mx;
            }
        }
    }
    __syncthreads();
    if (tid < 80) mg[tid] = fmaxf(mred[tid], mred[80 + tid]);
    __syncthreads();

    // pass 2: exp-sum and weighted Q2 dot (local max)
    #pragma unroll
    for (int mt = 0; mt < 5; ++mt) {
        #pragma unroll
        for (int e = 0; e < 8; ++e) {
            int g = 2 * e;
            int row = (g & 3) + 8 * (g >> 2) + 4 * kh;
            int i   = mt * 16 + (row >> 1);
            float m  = mg[i];
            float e0 = __expf(acc[mt][0][g] - m);
            float e1 = __expf(acc[mt][1][g] - m);
            float s = e0 + e1;
            float d = e0 * acc[mt][0][g + 1] + e1 * acc[mt][1][g + 1];
            #pragma unroll
            for (int off = 1; off <= 16; off <<= 1) {
                s += __shfl_xor(s, off, 64);
                d += __shfl_xor(d, off, 64);
            }
            if (nl == 0) {
                sred[wn * 80 + i] = s;
                dred[wn * 80 + i] = d;
            }
        }
    }
    __syncthreads();
    if (tid < 80) {
        size_t pb = ((size_t)b * 2 + rh) * NPI + mq * 80 + tid;
        pm[pb] = mg[tid];
        ps[pb] = sred[tid] + sred[80 + tid];
        pd[pb] = dred[tid] + dred[80 + tid];
    }
}

// ---- K2: combine the two r-halves (flash-style) ----
__launch_bounds__(256, 4)
__global__ void k_comb(const float* __restrict__ pm, const float* __restrict__ ps,
                       const float* __restrict__ pd, float* __restrict__ out) {
    int idx = blockIdx.x * 256 + threadIdx.x;   // 0..40959 = 128*320
    int b = idx / NPI;
    int i = idx - b * NPI;
    float m0 = pm[(size_t)(b * 2) * NPI + i];
    float m1 = pm[(size_t)(b * 2 + 1) * NPI + i];
    float m  = fmaxf(m0, m1);
    float w0 = __expf(m0 - m), w1 = __expf(m1 - m);
    float s = ps[(size_t)(b * 2) * NPI + i] * w0 + ps[(size_t)(b * 2 + 1) * NPI + i] * w1;
    float d = pd[(size_t)(b * 2) * NPI + i] * w0 + pd[(size_t)(b * 2 + 1) * NPI + i] * w1;
    if (i < NA) out[(size_t)b * NA + i] = d / s;
}

// ---- launcher ----
extern "C" void kernel_launch(void* const* d_in, const int* in_sizes, int n_in,
                              void* d_out, int out_size, void* d_ws, size_t ws_size,
                              hipStream_t stream) {
    const float* img = (const float*)d_in[0];
    const float* V   = (const float*)d_in[1];
    const float* W1  = (const float*)d_in[2];
    const float* W2  = (const float*)d_in[3];
    float* out = (float*)d_out;

    char* ws = (char*)d_ws;
    size_t off = 0;
    _Float16* Qb = (_Float16*)(ws + off); off += (size_t)NKC * MT * 32 * 2;
    float*    pm = (float*)(ws + off);    off += (size_t)NB * 2 * NPI * 4;
    float*    ps = (float*)(ws + off);    off += (size_t)NB * 2 * NPI * 4;
    float*    pd = (float*)(ws + off);    off += (size_t)NB * 2 * NPI * 4;

    k_q<<<dim3(NQ), 256, 0, stream>>>(V, W1, W2, Qb);
    k_fused<<<dim3(1024), 128, 0, stream>>>(img, Qb, pm, ps, pd);
    k_comb<<<dim3(160), 256, 0, stream>>>(pm, ps, pd, out);
}

// Round 10
// 276.186 us; speedup vs baseline: 1.0068x; 1.0068x over previous
//
#include <hip/hip_runtime.h>
#include <math.h>

#define NB   128
#define CF   1024
#define RR   256
#define NA   312
#define DV   300
#define MT   640
#define NKC  32
#define NQ   160
#define NPI  320          // padded i-pairs per (b,rh)
#define ACHUNK 40960      // Qb bytes per kc (640 rows x 64 B)
#define ATILE  20480      // LDS A: [4 kb][320 rows][16 B]
#define BTILE  8192       // LDS B: [4 oct][128 r][16 B f16]
#define BUFSZ  28672      // ATILE + BTILE

typedef _Float16 half8  __attribute__((ext_vector_type(8)));
typedef _Float16 half4  __attribute__((ext_vector_type(4)));
typedef float float16v  __attribute__((ext_vector_type(16)));
typedef float float4v   __attribute__((ext_vector_type(4)));
typedef float float2v   __attribute__((ext_vector_type(2)));

// async global->LDS, 16B/lane; dest = wave-uniform base + lane*16 (linear).
__device__ __forceinline__ void gll16(const void* g, void* l) {
    __builtin_amdgcn_global_load_lds(
        (const __attribute__((address_space(1))) void*)g,
        (__attribute__((address_space(3))) void*)l, 16, 0, 0);
}

// ---- K0: Q projection (pair-interleaved Qb rows: row 2i = Q1_i, 2i+1 = Q2_i) ----
__launch_bounds__(256, 4)
__global__ void k_q(const float* __restrict__ V, const float* __restrict__ W1,
                    const float* __restrict__ W2, _Float16* __restrict__ Qb) {
    int ib = blockIdx.x;
    int t  = threadIdx.x;
    bool isQ2 = ib >= 80;
    int i0l = (ib - (isQ2 ? 80 : 0)) * 4;
    __shared__ float inv4[4];
    float acc[4][4];
    #pragma unroll
    for (int ii = 0; ii < 4; ++ii)
        #pragma unroll
        for (int j = 0; j < 4; ++j) acc[ii][j] = 0.f;
    if (i0l < NA) {
        int row = t >> 6, l64 = t & 63;
        float s = 0.f;
        for (int v = l64; v < DV; v += 64) { float x = V[(i0l + row) * DV + v]; s += x * x; }
        #pragma unroll
        for (int o = 32; o; o >>= 1) s += __shfl_xor(s, o, 64);
        if (l64 == 0) inv4[row] = 1.f / fmaxf(sqrtf(s), 1e-12f);
        __syncthreads();
        const float* W  = isQ2 ? W2 : W1;
        const float* Vb = V + (size_t)i0l * DV;
        for (int v = 0; v < DV; v += 2) {
            float4v w0 = *(const float4v*)(W + (size_t)v * CF + t * 4);
            float4v w1 = *(const float4v*)(W + (size_t)(v + 1) * CF + t * 4);
            #pragma unroll
            for (int ii = 0; ii < 4; ++ii) {
                float a0 = Vb[(size_t)ii * DV + v];
                float a1 = Vb[(size_t)ii * DV + v + 1];
                #pragma unroll
                for (int j = 0; j < 4; ++j) acc[ii][j] += a0 * w0[j] + a1 * w1[j];
            }
        }
        #pragma unroll
        for (int ii = 0; ii < 4; ++ii)
            #pragma unroll
            for (int j = 0; j < 4; ++j) acc[ii][j] *= inv4[ii];
    }
    int fg = t >> 3;
    int fo = (t & 7) * 4;
    int q12 = isQ2 ? 1 : 0;
    #pragma unroll
    for (int ii = 0; ii < 4; ++ii) {
        half4 h;
        #pragma unroll
        for (int j = 0; j < 4; ++j) h[j] = (_Float16)acc[ii][j];
        *(half4*)&Qb[((size_t)fg * MT + (2 * (i0l + ii) + q12)) * 32 + fo] = h;
    }
}

// ---- K1: fused GEMM+norm+partial-softmax. block = (b, rh, mh):           ----
// ---- M=320 x N=128, 4 waves, 2 blocks/CU. B: dwordx2 regs->cvt->b128 LDS ----
__launch_bounds__(256, 2)
__global__ void k_fused(const float* __restrict__ img, const _Float16* __restrict__ Qb,
                        float* __restrict__ pm, float* __restrict__ ps,
                        float* __restrict__ pd) {
    __shared__ __align__(16) char smem_s[2 * BUFSZ];

    int lin = blockIdx.x;          // 0..511
    int b   = lin & 127;           // same b -> same XCD (lin%8 fixed per b)
    int sub = lin >> 7;            // 0..3
    int rh  = sub & 1;             // r-half
    int mh  = sub >> 1;            // M-half: Qb rows [mh*320, +320)

    int tid  = threadIdx.x;        // 0..255
    int lane = tid & 63;
    int w    = tid >> 6;           // 0..3
    int wm   = w >> 1;             // 0..1: pair rows [wm*80 pairs)
    int wn   = w & 1;              // 0..1: cols [wn*64, +64)
    int nl   = lane & 31;
    int kh   = lane >> 5;

    // A staging: slot s = kb*320 + r; 5 gll16/thread (1280 slots / 256).
    int aG[5];
    #pragma unroll
    for (int j = 0; j < 5; ++j) {
        int s  = tid + j * 256;
        int kb = s / 320;
        int r  = s % 320;
        aG[j] = ((mh * 320 + r) * 4 + kb) * 16;
    }
    const char* gA = (const char*)Qb;

    // B staging: thread owns octet fo2 = w, r-pair rp = lane (r = 2rp, 2rp+1).
    const float* gB = img + (size_t)b * CF * RR + (size_t)w * 8 * RR
                      + (size_t)rh * 128 + 2 * lane;

    float16v acc[5][2];
    #pragma unroll
    for (int i = 0; i < 5; ++i)
        #pragma unroll
        for (int j = 0; j < 2; ++j)
            #pragma unroll
            for (int gi = 0; gi < 16; ++gi) acc[i][j][gi] = 0.f;
    float ssq_e = 0.f, ssq_o = 0.f;        // cols 2rp / 2rp+1 of my octet
    float2v R0[8], R1[8];

    #define AGLL(kc_, bsel) do {                                                   \
        int kcl = (kc_) < NKC ? (kc_) : (NKC - 1);                                 \
        const char* aS = gA + (size_t)kcl * ACHUNK;                                \
        char* buf_ = smem_s + (int)(bsel) * BUFSZ;                                 \
        _Pragma("unroll")                                                          \
        for (int j = 0; j < 5; ++j) gll16(aS + aG[j], buf_ + (tid + j * 256) * 16); \
    } while (0)

    #define BLOAD(kc_, R) do {                                                     \
        int kcl = (kc_) < NKC ? (kc_) : (NKC - 1);                                 \
        const float* p = gB + (size_t)kcl * 32 * RR;                               \
        _Pragma("unroll")                                                          \
        for (int j = 0; j < 8; ++j) (R)[j] = *(const float2v*)(p + (size_t)j * RR); \
    } while (0)

    // convert tile's 2 r-columns, accumulate ssq, write 2 b128 to buf's B area
    #define CVTW(R, bsel) do {                                                     \
        half8 he, ho;                                                              \
        _Pragma("unroll")                                                          \
        for (int j = 0; j < 8; ++j) {                                              \
            float xe = (R)[j][0], xo = (R)[j][1];                                  \
            ssq_e += xe * xe; ssq_o += xo * xo;                                    \
            he[j] = (_Float16)xe; ho[j] = (_Float16)xo;                            \
        }                                                                          \
        char* bb = smem_s + (int)(bsel) * BUFSZ + ATILE + w * 2048 + lane * 32;    \
        *(half8*)bb = he;                                                          \
        *(half8*)(bb + 16) = ho;                                                   \
    } while (0)

    #define COMPUTE(bsel) do {                                                     \
        const char* Al = smem_s + (int)(bsel) * BUFSZ;                             \
        const char* Bl = Al + ATILE;                                               \
        _Pragma("unroll")                                                          \
        for (int ks = 0; ks < 2; ++ks) {                                           \
            int kb = ks * 2 + kh;                                                  \
            half8 bf0 = *(const half8*)(Bl + (kb * 128 + wn * 64 + nl) * 16);      \
            half8 bf1 = *(const half8*)(Bl + (kb * 128 + wn * 64 + 32 + nl) * 16); \
            _Pragma("unroll")                                                      \
            for (int mt = 0; mt < 5; ++mt) {                                       \
                half8 af = *(const half8*)(Al + (kb * 320 + wm * 160 + mt * 32 + nl) * 16); \
                acc[mt][0] = __builtin_amdgcn_mfma_f32_32x32x16_f16(af, bf0, acc[mt][0], 0, 0, 0); \
                acc[mt][1] = __builtin_amdgcn_mfma_f32_32x32x16_f16(af, bf1, acc[mt][1], 0, 0, 0); \
            }                                                                      \
        }                                                                          \
    } while (0)

    // prologue
    BLOAD(0, R0);                                      // [R0:8]
    AGLL(0, 0);                                        // [R0:8, A0:5]
    BLOAD(1, R1);                                      // [R0:8, A0:5, R1:8]
    asm volatile("s_waitcnt vmcnt(13)" ::: "memory");  // R0 landed
    CVTW(R0, 0);                                       // B(0) -> buf0
    asm volatile("s_waitcnt vmcnt(8)" ::: "memory");   // A0 landed
    asm volatile("s_waitcnt lgkmcnt(0)" ::: "memory");
    __builtin_amdgcn_s_barrier();                      // buf0 complete
    AGLL(1, 1);                                        // [R1:8, A1:5]  (invariant)
    __builtin_amdgcn_sched_barrier(0);

    // body macro: iter kc uses Rcur=B-regs(kc+1), loads Rnxt=B-regs(kc+2)
    #define ITER(kc_, Rcur, Rnxt) do {                                             \
        BLOAD((kc_) + 2, Rnxt);                        /* [Rcur:8, A:5, Rnxt:8] */ \
        asm volatile("s_waitcnt vmcnt(13)" ::: "memory"); /* Rcur landed */        \
        CVTW(Rcur, ((kc_) + 1) & 1);                   /* B(kc+1) -> other buf */  \
        __builtin_amdgcn_sched_barrier(0);                                         \
        __builtin_amdgcn_s_setprio(1);                                             \
        COMPUTE((kc_) & 1);                                                        \
        __builtin_amdgcn_s_setprio(0);                                             \
        __builtin_amdgcn_sched_barrier(0);                                         \
        asm volatile("s_waitcnt vmcnt(8)" ::: "memory");  /* A(kc+1) landed */     \
        asm volatile("s_waitcnt lgkmcnt(0)" ::: "memory");                         \
        __builtin_amdgcn_s_barrier();                  /* buf(kc+1) complete */    \
        AGLL((kc_) + 2, (kc_) & 1);                    /* [Rnxt:8, A(kc+2):5] */   \
        __builtin_amdgcn_sched_barrier(0);                                         \
    } while (0)

    #pragma unroll 1
    for (int kc = 0; kc < NKC - 2; kc += 2) {
        ITER(kc,     R1, R0);
        ITER(kc + 1, R0, R1);
    }
    ITER(NKC - 2, R1, R0);                             // kc=30 (CVTW B(31); dup loads)
    // final tile NKC-1 sits complete in buf((NKC-1)&1); no staging left to wait on
    __builtin_amdgcn_s_setprio(1);
    COMPUTE((NKC - 1) & 1);
    __builtin_amdgcn_s_setprio(0);
    asm volatile("s_waitcnt vmcnt(0) lgkmcnt(0)" ::: "memory");
    __builtin_amdgcn_s_barrier();
    __builtin_amdgcn_sched_barrier(0);
    #undef ITER
    #undef AGLL
    #undef BLOAD
    #undef CVTW
    #undef COMPUTE

    // ---- epilogue (aliases smem_s) ----
    float* ssq_lds = (float*)smem_s;              // [4 oct][64 rp][2] = 2 KB
    float* ssq_r   = (float*)(smem_s + 2048);     // [128]
    float* mred    = (float*)(smem_s + 2560);     // [2][160]
    float* mg      = (float*)(smem_s + 3840);     // [160]
    float* sred    = (float*)(smem_s + 4480);     // [2][160]
    float* dred    = (float*)(smem_s + 5760);     // [2][160]

    ssq_lds[(w * 64 + lane) * 2 + 0] = ssq_e;
    ssq_lds[(w * 64 + lane) * 2 + 1] = ssq_o;
    __syncthreads();
    if (tid < 128) {
        int rp = tid >> 1, par = tid & 1;
        float sv = 0.f;
        #pragma unroll
        for (int o = 0; o < 4; ++o) sv += ssq_lds[((o * 64 + rp) * 2) + par];
        ssq_r[tid] = sv;
    }
    __syncthreads();
    int c0 = wn * 64 + nl;
    float iv0 = 1.f / fmaxf(sqrtf(ssq_r[c0]), 1e-12f);
    float iv1 = 1.f / fmaxf(sqrtf(ssq_r[c0 + 32]), 1e-12f);
    __syncthreads();                                  // ssq_lds region reused below
    #pragma unroll
    for (int mt = 0; mt < 5; ++mt)
        #pragma unroll
        for (int gi = 0; gi < 16; ++gi) {
            acc[mt][0][gi] *= iv0;
            acc[mt][1][gi] *= iv1;
        }

    // pass 1: per-pair max over this block's 128 r
    #pragma unroll
    for (int mt = 0; mt < 5; ++mt) {
        #pragma unroll
        for (int e = 0; e < 8; ++e) {
            int g = 2 * e;
            float mx = fmaxf(acc[mt][0][g], acc[mt][1][g]);
            #pragma unroll
            for (int off = 1; off <= 16; off <<= 1)
                mx = fmaxf(mx, __shfl_xor(mx, off, 64));
            if (nl == 0) {
                int row = (g & 3) + 8 * (g >> 2) + 4 * kh;     // even, 0..30
                mred[wn * 160 + wm * 80 + mt * 16 + (row >> 1)] = mx;
            }
        }
    }
    __syncthreads();
    if (tid < 160) mg[tid] = fmaxf(mred[tid], mred[160 + tid]);
    __syncthreads();

    // pass 2: exp-sum and weighted Q2 dot (local max)
    #pragma unroll
    for (int mt = 0; mt < 5; ++mt) {
        #pragma unroll
        for (int e = 0; e < 8; ++e) {
            int g = 2 * e;
            int row = (g & 3) + 8 * (g >> 2) + 4 * kh;
            int i   = wm * 80 + mt * 16 + (row >> 1);
            float m  = mg[i];
            float e0 = __expf(acc[mt][0][g] - m);
            float e1 = __expf(acc[mt][1][g] - m);
            float s = e0 + e1;
            float d = e0 * acc[mt][0][g + 1] + e1 * acc[mt][1][g + 1];
            #pragma unroll
            for (int off = 1; off <= 16; off <<= 1) {
                s += __shfl_xor(s, off, 64);
                d += __shfl_xor(d, off, 64);
            }
            if (nl == 0) {
                sred[wn * 160 + i] = s;
                dred[wn * 160 + i] = d;
            }
        }
    }
    __syncthreads();
    if (tid < 160) {
        size_t pb = ((size_t)b * 2 + rh) * NPI + mh * 160 + tid;
        pm[pb] = mg[tid];
        ps[pb] = sred[tid] + sred[160 + tid];
        pd[pb] = dred[tid] + dred[160 + tid];
    }
}

// ---- K2: combine the two r-halves (flash-style) ----
__launch_bounds__(256, 4)
__global__ void k_comb(const float* __restrict__ pm, const float* __restrict__ ps,
                       const float* __restrict__ pd, float* __restrict__ out) {
    int idx = blockIdx.x * 256 + threadIdx.x;   // 0..40959 = 128*320
    int b = idx / NPI;
    int i = idx - b * NPI;
    float m0 = pm[(size_t)(b * 2) * NPI + i];
    float m1 = pm[(size_t)(b * 2 + 1) * NPI + i];
    float m  = fmaxf(m0, m1);
    float w0 = __expf(m0 - m), w1 = __expf(m1 - m);
    float s = ps[(size_t)(b * 2) * NPI + i] * w0 + ps[(size_t)(b * 2 + 1) * NPI + i] * w1;
    float d = pd[(size_t)(b * 2) * NPI + i] * w0 + pd[(size_t)(b * 2 + 1) * NPI + i] * w1;
    if (i < NA) out[(size_t)b * NA + i] = d / s;
}

// ---- launcher ----
extern "C" void kernel_launch(void* const* d_in, const int* in_sizes, int n_in,
                              void* d_out, int out_size, void* d_ws, size_t ws_size,
                              hipStream_t stream) {
    const float* img = (const float*)d_in[0];
    const float* V   = (const float*)d_in[1];
    const float* W1  = (const float*)d_in[2];
    const float* W2  = (const float*)d_in[3];
    float* out = (float*)d_out;

    char* ws = (char*)d_ws;
    size_t off = 0;
    _Float16* Qb = (_Float16*)(ws + off); off += (size_t)NKC * MT * 32 * 2;
    float*    pm = (float*)(ws + off);    off += (size_t)NB * 2 * NPI * 4;
    float*    ps = (float*)(ws + off);    off += (size_t)NB * 2 * NPI * 4;
    float*    pd = (float*)(ws + off);    off += (size_t)NB * 2 * NPI * 4;

    k_q<<<dim3(NQ), 256, 0, stream>>>(V, W1, W2, Qb);
    k_fused<<<dim3(512), 256, 0, stream>>>(img, Qb, pm, ps, pd);
    k_comb<<<dim3(160), 256, 0, stream>>>(pm, ps, pd, out);
}